// Round 15
// baseline (3103.773 us; speedup 1.0000x reference)
//
#include <hip/hip_runtime.h>

#define HID 64
#define TSTEPS 64
#define NTHREADS 256
#define ROWS_PB 64

typedef __attribute__((ext_vector_type(8))) short bf16x8;
typedef __attribute__((ext_vector_type(4))) float f32x4;

__device__ __forceinline__ float fast_exp2(float x) { return __builtin_amdgcn_exp2f(x); }
__device__ __forceinline__ float fast_rcp(float x)  { return __builtin_amdgcn_rcpf(x); }
#define LOG2E 1.44269504088896341f
#define TWO_L 2.88539008177792682f   // 2*log2(e)

__device__ __forceinline__ unsigned short f2bf(float f) {   // RNE fp32->bf16
    unsigned u = __float_as_uint(f);
    u = u + 0x7fffu + ((u >> 16) & 1u);
    return (unsigned short)(u >> 16);
}
__device__ __forceinline__ float bfh(unsigned short h) { return __uint_as_float(((unsigned)h) << 16); }
__device__ __forceinline__ unsigned cvt_pk_bf16(float a, float b) {  // low16=bf(a), high16=bf(b)
    unsigned r;
    asm("v_cvt_pk_bf16_f32 %0, %1, %2" : "=v"(r) : "v"(a), "v"(b));
    return r;
}

// k-space permutation pi(p) = {p5, p2, p4, p3, p1, p0}:
// B-frag slot (kc*32+8g+j) holds h-unit 16*(2kc+(j>>2)) + 4g + (j&3), so the
// D-layout activations write hB in place (hB[4u+e] = hn[u][e]) with no
// cross-lane exchange. Whh columns + mog/proj tables staged with the same pi.
__device__ __forceinline__ int permk(int p) {
    return (p & 0x23) | ((p & 0x04) << 2) | ((p & 0x18) >> 1);
}

// ---------------- LDS layout (bytes) ----------------
//   [0,     32768)  WA   : 16 tiles x 2 frags (bf16 kc0,kc1) x 64 lanes x 16B
//                   i/f/o tiles pre-scaled by -log2e, g tiles by +2log2e
//   [32768, 36864)  EXT  : 16 tiles x 16 rows x 16B (bias+Wih A-frag, g==0 lanes)
//   [36864, 36880)  ZERO : 16B zeros (broadcast for g>0 lanes)
//   [36880, 39972)  MOG  : fp32 tables (float offsets below), pi-permuted, -L scaled
//   [40960, 49152)  XSEQ : fp16 [t=64][row=64]
// stem overlay: ping [0,17408), pong [17408,34816) -- dead before WA/EXT/MOG staging
#define OFF_WA    0
#define OFF_EXT   32768
#define OFF_ZERO  36864
#define OFF_MOGB  36880
#define OFF_XSEQ  40960
#define SMEM_TOTAL 49152

#define M0W 0
#define M2W 64
#define M4W 128
#define M1W 192
#define M1B 256
#define M3W 320
#define M3B 384
#define WPo 448
#define BPo 768

__global__ __launch_bounds__(NTHREADS, 3) void moglstm_mfma11(
    const float* __restrict__ x,
    const float* __restrict__ W1, const float* __restrict__ B1,
    const float* __restrict__ W2, const float* __restrict__ B2,
    const float* __restrict__ W3, const float* __restrict__ B3,
    const float* __restrict__ W4, const float* __restrict__ B4,
    const float* __restrict__ M0w, const float* __restrict__ M0b,
    const float* __restrict__ M1w, const float* __restrict__ M1b,
    const float* __restrict__ M2w, const float* __restrict__ M2b,
    const float* __restrict__ M3w, const float* __restrict__ M3b,
    const float* __restrict__ M4w, const float* __restrict__ M4b,
    const float* __restrict__ Wih, const float* __restrict__ Bih,
    const float* __restrict__ Whh, const float* __restrict__ Bhh,
    const float* __restrict__ Wp,  const float* __restrict__ Bp,
    float* __restrict__ out)
{
    __shared__ __align__(16) char smem[SMEM_TOTAL];
    bf16x8*   WA     = (bf16x8*)(smem + OFF_WA);
    float*    mogf   = (float*)(smem + OFF_MOGB);
    _Float16* sXseqH = (_Float16*)(smem + OFF_XSEQ);
    float*    ping   = (float*)(smem);
    float*    pong   = (float*)(smem + 17408);

    const int tid = threadIdx.x;
    const long rowbase = (long)blockIdx.x * ROWS_PB;

    // ================= MLP stem (4x Linear(64->64)+ReLU), 64 rows =================
    for (int i = tid; i < ROWS_PB * 16; i += NTHREADS) {
        int r = i >> 4, c4 = i & 15;
        *(float4*)&ping[r * 68 + c4 * 4] = ((const float4*)x)[(rowbase + r) * 16 + c4];
    }
    __syncthreads();
    {
        const int sr = tid & 63;    // row
        const int sq = tid >> 6;    // quarter (wave-uniform) -> units sq*16..+15
        const float* Ws[4] = {W1, W2, W3, W4};
        const float* Bs[4] = {B1, B2, B3, B4};
        float rin[HID];
        #pragma unroll
        for (int L = 0; L < 4; ++L) {
            const float* SRC = (L & 1) ? pong : ping;
            float* DST       = (L & 1) ? ping : pong;
            #pragma unroll
            for (int k4 = 0; k4 < 16; ++k4) {
                float4 v = *(const float4*)&SRC[sr * 68 + k4 * 4];
                rin[4*k4+0] = v.x; rin[4*k4+1] = v.y; rin[4*k4+2] = v.z; rin[4*k4+3] = v.w;
            }
            __syncthreads();
            const float* W = Ws[L];
            const float* Bb = Bs[L];
            #pragma unroll
            for (int jj4 = 0; jj4 < 4; ++jj4) {
                float o[4];
                #pragma unroll
                for (int e = 0; e < 4; ++e) {
                    int j = sq * 16 + jj4 * 4 + e;
                    float a = Bb[j];
                    const float4* wr = (const float4*)(W + j * 64);  // wave-uniform -> s_load
                    #pragma unroll
                    for (int k4 = 0; k4 < 16; ++k4) {
                        float4 w = wr[k4];
                        a += w.x*rin[4*k4] + w.y*rin[4*k4+1] + w.z*rin[4*k4+2] + w.w*rin[4*k4+3];
                    }
                    o[e] = fmaxf(a, 0.0f);
                }
                *(float4*)&DST[sr * 68 + sq * 16 + jj4 * 4] = make_float4(o[0], o[1], o[2], o[3]);
            }
            __syncthreads();
        }
    }
    // final stem output in ping (L4 wrote pong->ping)

    // ---- transpose stem output to fp16 XSEQ[t][row] (disjoint region) ----
    for (int i = tid; i < TSTEPS * ROWS_PB; i += NTHREADS) {
        int t = i >> 6, r = i & 63;
        sXseqH[i] = (_Float16)ping[r * 68 + t];
    }
    __syncthreads();   // ping reads done; WA/EXT/ZERO/MOG may overwrite overlay

    // ============ stage Whh bf16 A-frags, pi-permuted cols, exp2-prescaled ============
    for (int i = tid; i < 2048; i += NTHREADS) {
        int ln = i & 63, kc = (i >> 6) & 1, tt = i >> 7;
        int gi = tt >> 2, u = tt & 3;          // gi: 0=i 1=f 2=g 3=o
        int r = ln & 15, g = ln >> 4;
        float scl = (gi == 2) ? TWO_L : -LOG2E;
        const float* src = Whh + (gi * 64 + u * 16 + r) * 64;
        union { bf16x8 v; unsigned short s[8]; } f;
        #pragma unroll
        for (int j = 0; j < 8; ++j)
            f.s[j] = f2bf(scl * src[kc * 32 + 16 * (j >> 2) + 4 * g + (j & 3)]);
        WA[(tt * 2 + kc) * 64 + ln] = f.v;
    }
    // compact ext frag (scaled): A[row r][k0..4] = {wih_hi, wih_hi, wih_lo, gb_hi, gb_lo}
    {
        int tt = tid >> 4, r = tid & 15;
        int gi = tt >> 2;
        float scl = (gi == 2) ? TWO_L : -LOG2E;
        int G = gi * 64 + (tt & 3) * 16 + r;
        float wih = scl * Wih[G];
        float gb  = scl * (Bih[G] + Bhh[G]);
        unsigned short wh = f2bf(wih);
        unsigned short wl = f2bf(wih - bfh(wh));
        unsigned short gh = f2bf(gb);
        unsigned short gl = f2bf(gb - bfh(gh));
        union { bf16x8 v; unsigned u[4]; } f;
        f.u[0] = (unsigned)wh | ((unsigned)wh << 16);
        f.u[1] = (unsigned)wl | ((unsigned)gh << 16);
        f.u[2] = (unsigned)gl;
        f.u[3] = 0u;
        *(bf16x8*)(smem + OFF_EXT + tt * 256 + r * 16) = f.v;
    }
    if (tid < 4) ((float*)(smem + OFF_ZERO))[tid] = 0.0f;
    // mog tables: pi-permuted AND pre-scaled by -log2e (sig args in exp2 units)
    if (tid < 64) {
        int s = permk(tid);
        mogf[M0W + tid] = -LOG2E * M0w[s];
        mogf[M2W + tid] = -LOG2E * M2w[s];
        mogf[M4W + tid] = -LOG2E * M4w[s];
        mogf[M1W + tid] = -LOG2E * M1w[s];
        mogf[M1B + tid] = -LOG2E * M1b[s];
        mogf[M3W + tid] = -LOG2E * M3w[s];
        mogf[M3B + tid] = -LOG2E * M3b[s];
    }
    for (int i = tid; i < 320; i += NTHREADS)
        mogf[WPo + i] = Wp[(i & ~63) + permk(i & 63)];
    if (tid < 5) mogf[BPo + tid] = Bp[tid];
    __syncthreads();

    // ===================== mogrifier-LSTM recurrence =====================
    const int lane = tid & 63;
    const int wv   = tid >> 6;       // wave 0..3 -> rows wv*16..+15
    const int g_   = lane >> 4;      // 0..3
    const int n    = lane & 15;      // batchrow within wave (A-row / D-col)
    const int myrow = wv * 16 + n;

    const char* extb    = smem + ((g_ == 0) ? (OFF_EXT + n * 16) : OFF_ZERO);
    const int   extstep = (g_ == 0) ? 256 : 0;
    const float m0b_s = -LOG2E * M0b[0];
    const float m2b_s = -LOG2E * M2b[0];
    const float m4b_s = -LOG2E * M4b[0];

    // hB[4u+e] = h[unit 16u + 4g_ + e] of row n (fp32; equals B-frag order via pi)
    float hB[16];
    f32x4 cst[4];
    #pragma unroll
    for (int i = 0; i < 16; ++i) hB[i] = 0.0f;
    #pragma unroll
    for (int u = 0; u < 4; ++u) cst[u] = (f32x4){0.0f, 0.0f, 0.0f, 0.0f};

// q is already -L*(dot+bias); 2*sig = rcp(0.5 + 0.5*exp2(q))
#define MOG_DOT(MOFF, BIAS)                                                   \
    {                                                                         \
        float4 w0 = *(const float4*)&mogf[(MOFF) + g_ * 8];                   \
        float4 w1 = *(const float4*)&mogf[(MOFF) + g_ * 8 + 4];               \
        float4 w2 = *(const float4*)&mogf[(MOFF) + 32 + g_ * 8];              \
        float4 w3 = *(const float4*)&mogf[(MOFF) + 32 + g_ * 8 + 4];          \
        float p = w0.x*hB[0] + w0.y*hB[1] + w0.z*hB[2] + w0.w*hB[3]           \
                + w1.x*hB[4] + w1.y*hB[5] + w1.z*hB[6] + w1.w*hB[7]           \
                + w2.x*hB[8] + w2.y*hB[9] + w2.z*hB[10] + w2.w*hB[11]         \
                + w3.x*hB[12] + w3.y*hB[13] + w3.z*hB[14] + w3.w*hB[15];      \
        p += __shfl_xor(p, 16);                                               \
        p += __shfl_xor(p, 32);                                               \
        float t_ = fast_exp2(p + (BIAS));                                     \
        xt *= fast_rcp(0.5f + 0.5f * t_);                                     \
    }

#define MOG_SCALE(WOFF, BOFF)                                                 \
    {                                                                         \
        _Pragma("unroll")                                                     \
        for (int kc = 0; kc < 2; ++kc) {                                      \
            _Pragma("unroll")                                                 \
            for (int q = 0; q < 2; ++q) {                                     \
                float4 w4 = *(const float4*)&mogf[(WOFF) + kc*32 + g_*8 + q*4]; \
                float4 b4 = *(const float4*)&mogf[(BOFF) + kc*32 + g_*8 + q*4]; \
                int bse = kc * 8 + q * 4;                                     \
                hB[bse+0] *= fast_rcp(0.5f + 0.5f * fast_exp2(xt * w4.x + b4.x)); \
                hB[bse+1] *= fast_rcp(0.5f + 0.5f * fast_exp2(xt * w4.y + b4.y)); \
                hB[bse+2] *= fast_rcp(0.5f + 0.5f * fast_exp2(xt * w4.z + b4.z)); \
                hB[bse+3] *= fast_rcp(0.5f + 0.5f * fast_exp2(xt * w4.w + b4.w)); \
            }                                                                 \
        }                                                                     \
    }

    #pragma unroll 1
    for (int t = 0; t < TSTEPS; ++t) {
        float xt = (float)sXseqH[t * 64 + myrow];   // fp16 broadcast ds_read

        // ---- mogrifier (prescaled args, folded 2x) ----
        MOG_DOT(M0W, m0b_s)
        MOG_SCALE(M1W, M1B)
        MOG_DOT(M2W, m2b_s)
        MOG_SCALE(M3W, M3B)
        MOG_DOT(M4W, m4b_s)

        // ---- B-frags: h -> split bf16 ----
        union uf8 { bf16x8 v; unsigned u[4]; };
        uf8 bhi0, bhi1, blo0, blo1, bext;
        #pragma unroll
        for (int kc = 0; kc < 2; ++kc) {
            #pragma unroll
            for (int jp = 0; jp < 4; ++jp) {
                float a = hB[kc * 8 + 2 * jp], b = hB[kc * 8 + 2 * jp + 1];
                unsigned hi = cvt_pk_bf16(a, b);
                float ah = __uint_as_float(hi << 16);
                float bh = __uint_as_float(hi & 0xffff0000u);
                unsigned lo = cvt_pk_bf16(a - ah, b - bh);
                if (kc == 0) { bhi0.u[jp] = hi; blo0.u[jp] = lo; }
                else         { bhi1.u[jp] = hi; blo1.u[jp] = lo; }
            }
        }
        {   // ext B: k-slots {xt_hi, xt_lo, xt_hi, 1, 1, 0, 0, 0}
            unsigned xh = cvt_pk_bf16(xt, xt) & 0xffffu;
            float xl = xt - bfh((unsigned short)xh);
            unsigned xlp = cvt_pk_bf16(xl, xl) & 0xffffu;
            bext.u[0] = xh | (xlp << 16);
            bext.u[1] = xh | (0x3F80u << 16);
            bext.u[2] = 0x3F80u;
            bext.u[3] = 0u;
        }

        // gates (exp2-units) = scl*(Whh@h + xt*Wih + b)  (5 MFMAs per tile)
        auto gate_tile = [&](int tt) -> f32x4 {
            bf16x8 whi0 = WA[(tt * 2 + 0) * 64 + lane];
            bf16x8 whi1 = WA[(tt * 2 + 1) * 64 + lane];
            bf16x8 wext = *(const bf16x8*)(extb + tt * extstep);
            f32x4 d = {0.0f, 0.0f, 0.0f, 0.0f};
            d = __builtin_amdgcn_mfma_f32_16x16x32_bf16(wext, bext.v, d, 0, 0, 0);
            d = __builtin_amdgcn_mfma_f32_16x16x32_bf16(whi0, bhi0.v, d, 0, 0, 0);
            d = __builtin_amdgcn_mfma_f32_16x16x32_bf16(whi1, bhi1.v, d, 0, 0, 0);
            d = __builtin_amdgcn_mfma_f32_16x16x32_bf16(whi0, blo0.v, d, 0, 0, 0);
            d = __builtin_amdgcn_mfma_f32_16x16x32_bf16(whi1, blo1.v, d, 0, 0, 0);
            return d;
        };

        // ---- per unit-group u: fused activations (8 trans/element) ----
        // ai = -L*i, af = -L*f, ag = 2L*g, ao = -L*o  (directly exp2-ready)
        #pragma unroll
        for (int u = 0; u < 4; ++u) {
            f32x4 ai = gate_tile(u);
            f32x4 af = gate_tile(4 + u);
            f32x4 ag = gate_tile(8 + u);
            f32x4 ao = gate_tile(12 + u);
            #pragma unroll
            for (int e = 0; e < 4; ++e) {
                // sig(i)*tanh(g) = (B-1)/((1+A)(1+B)); A=inf -> r=0 -> 0 (correct)
                float A  = fast_exp2(ai[e]);
                float Bg = fminf(fast_exp2(ag[e]), 3.0e8f);
                float r  = fast_rcp((1.0f + A) * (1.0f + Bg));
                float p1 = (Bg - 1.0f) * r;
                float sf = fast_rcp(1.0f + fast_exp2(af[e]));      // sig(f)
                float cc = sf * cst[u][e] + p1;
                cst[u][e] = cc;
                float Ao = fast_exp2(ao[e]);
                float Bc = fminf(fast_exp2(TWO_L * cc), 3.0e8f);
                float rc = fast_rcp((1.0f + Ao) * (1.0f + Bc));
                hB[u * 4 + e] = (Bc - 1.0f) * rc;                  // sig(o)*tanh(c)
            }
        }
    }

    // ===================== projection: out = h @ Wp^T + Bp =====================
    #pragma unroll
    for (int p = 0; p < 5; ++p) {
        float ap = 0.0f;
        #pragma unroll
        for (int kc = 0; kc < 2; ++kc) {
            #pragma unroll
            for (int q = 0; q < 2; ++q) {
                float4 w = *(const float4*)&mogf[WPo + p * 64 + kc * 32 + g_ * 8 + q * 4];
                ap += w.x * hB[kc * 8 + q * 4 + 0] + w.y * hB[kc * 8 + q * 4 + 1]
                    + w.z * hB[kc * 8 + q * 4 + 2] + w.w * hB[kc * 8 + q * 4 + 3];
            }
        }
        ap += __shfl_xor(ap, 16);
        ap += __shfl_xor(ap, 32);
        if (g_ == 0)
            out[(rowbase + myrow) * 5 + p] = ap + mogf[BPo + p];
    }
}

extern "C" void kernel_launch(void* const* d_in, const int* in_sizes, int n_in,
                              void* d_out, int out_size, void* d_ws, size_t ws_size,
                              hipStream_t stream) {
    const float* x   = (const float*)d_in[0];
    const float* W1  = (const float*)d_in[1];
    const float* B1  = (const float*)d_in[2];
    const float* W2  = (const float*)d_in[3];
    const float* B2  = (const float*)d_in[4];
    const float* W3  = (const float*)d_in[5];
    const float* B3  = (const float*)d_in[6];
    const float* W4  = (const float*)d_in[7];
    const float* B4  = (const float*)d_in[8];
    const float* M0w = (const float*)d_in[9];
    const float* M0b = (const float*)d_in[10];
    const float* M1w = (const float*)d_in[11];
    const float* M1b = (const float*)d_in[12];
    const float* M2w = (const float*)d_in[13];
    const float* M2b = (const float*)d_in[14];
    const float* M3w = (const float*)d_in[15];
    const float* M3b = (const float*)d_in[16];
    const float* M4w = (const float*)d_in[17];
    const float* M4b = (const float*)d_in[18];
    const float* Wih = (const float*)d_in[19];
    const float* Bih = (const float*)d_in[20];
    const float* Whh = (const float*)d_in[21];
    const float* Bhh = (const float*)d_in[22];
    const float* Wp  = (const float*)d_in[23];
    const float* Bp  = (const float*)d_in[24];

    int B = in_sizes[0] / HID;          // 262144
    int nblocks = B / ROWS_PB;          // 4096

    hipLaunchKernelGGL(moglstm_mfma11, dim3(nblocks), dim3(NTHREADS), 0, stream,
                       x, W1, B1, W2, B2, W3, B3, W4, B4,
                       M0w, M0b, M1w, M1b, M2w, M2b, M3w, M3b, M4w, M4b,
                       Wih, Bih, Whh, Bhh, Wp, Bp, (float*)d_out);
}

// Round 16
// 2188.618 us; speedup vs baseline: 1.4181x; 1.4181x over previous
//
#include <hip/hip_runtime.h>

#define HID 64
#define TSTEPS 64
#define NTHREADS 256
#define ROWS_PB 64

typedef __attribute__((ext_vector_type(8))) short bf16x8;
typedef __attribute__((ext_vector_type(4))) float f32x4;

__device__ __forceinline__ float fast_exp2(float x) { return __builtin_amdgcn_exp2f(x); }
__device__ __forceinline__ float fast_rcp(float x)  { return __builtin_amdgcn_rcpf(x); }
#define LOG2E 1.44269504088896341f
#define TWO_L 2.88539008177792682f   // 2*log2(e)

__device__ __forceinline__ unsigned short f2bf(float f) {   // RNE fp32->bf16
    unsigned u = __float_as_uint(f);
    u = u + 0x7fffu + ((u >> 16) & 1u);
    return (unsigned short)(u >> 16);
}
__device__ __forceinline__ float bfh(unsigned short h) { return __uint_as_float(((unsigned)h) << 16); }
__device__ __forceinline__ unsigned cvt_pk_bf16(float a, float b) {  // low16=bf(a), high16=bf(b)
    unsigned r;
    asm("v_cvt_pk_bf16_f32 %0, %1, %2" : "=v"(r) : "v"(a), "v"(b));
    return r;
}

// k-space permutation pi(p) = {p5, p2, p4, p3, p1, p0}:
// B-frag slot (kc*32+8g+j) holds h-unit 16*(2kc+(j>>2)) + 4g + (j&3), so the
// D-layout activations write hB in place (hB[4u+e] = hn[u][e]) with no
// cross-lane exchange. Whh columns + mog/proj tables staged with the same pi.
__device__ __forceinline__ int permk(int p) {
    return (p & 0x23) | ((p & 0x04) << 2) | ((p & 0x18) >> 1);
}

// ---------------- LDS layout (bytes) ----------------
//   [0,     32768)  WA   : 16 tiles x 2 frags (bf16 kc0,kc1) x 64 lanes x 16B
//                   i/f/o tiles pre-scaled by -log2e, g tiles by +2log2e
//   [32768, 36864)  EXT  : 16 tiles x 16 rows x 16B (bias+Wih A-frag, g==0 lanes)
//   [36864, 36880)  ZERO : 16B zeros (broadcast for g>0 lanes)
//   [36880, 39972)  MOG  : fp32 tables (float offsets below), pi-permuted, -L scaled
//   [40960, 49152)  XSEQ : fp16 [t=64][row=64]
// stem overlay: ping [0,17408), pong [17408,34816) -- dead before WA/EXT/MOG staging
#define OFF_WA    0
#define OFF_EXT   32768
#define OFF_ZERO  36864
#define OFF_MOGB  36880
#define OFF_XSEQ  40960
#define SMEM_TOTAL 49152

#define M0W 0
#define M2W 64
#define M4W 128
#define M1W 192
#define M1B 256
#define M3W 320
#define M3B 384
#define WPo 448
#define BPo 768

__global__ __launch_bounds__(NTHREADS, 2) void moglstm_mfma9(
    const float* __restrict__ x,
    const float* __restrict__ W1, const float* __restrict__ B1,
    const float* __restrict__ W2, const float* __restrict__ B2,
    const float* __restrict__ W3, const float* __restrict__ B3,
    const float* __restrict__ W4, const float* __restrict__ B4,
    const float* __restrict__ M0w, const float* __restrict__ M0b,
    const float* __restrict__ M1w, const float* __restrict__ M1b,
    const float* __restrict__ M2w, const float* __restrict__ M2b,
    const float* __restrict__ M3w, const float* __restrict__ M3b,
    const float* __restrict__ M4w, const float* __restrict__ M4b,
    const float* __restrict__ Wih, const float* __restrict__ Bih,
    const float* __restrict__ Whh, const float* __restrict__ Bhh,
    const float* __restrict__ Wp,  const float* __restrict__ Bp,
    float* __restrict__ out)
{
    __shared__ __align__(16) char smem[SMEM_TOTAL];
    bf16x8*   WA     = (bf16x8*)(smem + OFF_WA);
    float*    mogf   = (float*)(smem + OFF_MOGB);
    _Float16* sXseqH = (_Float16*)(smem + OFF_XSEQ);
    float*    ping   = (float*)(smem);
    float*    pong   = (float*)(smem + 17408);

    const int tid = threadIdx.x;
    const long rowbase = (long)blockIdx.x * ROWS_PB;

    // ================= MLP stem (4x Linear(64->64)+ReLU), 64 rows =================
    for (int i = tid; i < ROWS_PB * 16; i += NTHREADS) {
        int r = i >> 4, c4 = i & 15;
        *(float4*)&ping[r * 68 + c4 * 4] = ((const float4*)x)[(rowbase + r) * 16 + c4];
    }
    __syncthreads();
    {
        const int sr = tid & 63;    // row
        const int sq = tid >> 6;    // quarter (wave-uniform) -> units sq*16..+15
        const float* Ws[4] = {W1, W2, W3, W4};
        const float* Bs[4] = {B1, B2, B3, B4};
        float rin[HID];
        #pragma unroll
        for (int L = 0; L < 4; ++L) {
            const float* SRC = (L & 1) ? pong : ping;
            float* DST       = (L & 1) ? ping : pong;
            #pragma unroll
            for (int k4 = 0; k4 < 16; ++k4) {
                float4 v = *(const float4*)&SRC[sr * 68 + k4 * 4];
                rin[4*k4+0] = v.x; rin[4*k4+1] = v.y; rin[4*k4+2] = v.z; rin[4*k4+3] = v.w;
            }
            __syncthreads();
            const float* W = Ws[L];
            const float* Bb = Bs[L];
            #pragma unroll
            for (int jj4 = 0; jj4 < 4; ++jj4) {
                float o[4];
                #pragma unroll
                for (int e = 0; e < 4; ++e) {
                    int j = sq * 16 + jj4 * 4 + e;
                    float a = Bb[j];
                    const float4* wr = (const float4*)(W + j * 64);  // wave-uniform -> s_load
                    #pragma unroll
                    for (int k4 = 0; k4 < 16; ++k4) {
                        float4 w = wr[k4];
                        a += w.x*rin[4*k4] + w.y*rin[4*k4+1] + w.z*rin[4*k4+2] + w.w*rin[4*k4+3];
                    }
                    o[e] = fmaxf(a, 0.0f);
                }
                *(float4*)&DST[sr * 68 + sq * 16 + jj4 * 4] = make_float4(o[0], o[1], o[2], o[3]);
            }
            __syncthreads();
        }
    }
    // final stem output in ping (L4 wrote pong->ping)

    // ---- transpose stem output to fp16 XSEQ[t][row] (disjoint region) ----
    for (int i = tid; i < TSTEPS * ROWS_PB; i += NTHREADS) {
        int t = i >> 6, r = i & 63;
        sXseqH[i] = (_Float16)ping[r * 68 + t];
    }
    __syncthreads();   // ping reads done; WA/EXT/ZERO/MOG may overwrite overlay

    // ============ stage Whh bf16 A-frags, pi-permuted cols, exp2-prescaled ============
    for (int i = tid; i < 2048; i += NTHREADS) {
        int ln = i & 63, kc = (i >> 6) & 1, tt = i >> 7;
        int gi = tt >> 2, u = tt & 3;          // gi: 0=i 1=f 2=g 3=o
        int r = ln & 15, g = ln >> 4;
        float scl = (gi == 2) ? TWO_L : -LOG2E;
        const float* src = Whh + (gi * 64 + u * 16 + r) * 64;
        union { bf16x8 v; unsigned short s[8]; } f;
        #pragma unroll
        for (int j = 0; j < 8; ++j)
            f.s[j] = f2bf(scl * src[kc * 32 + 16 * (j >> 2) + 4 * g + (j & 3)]);
        WA[(tt * 2 + kc) * 64 + ln] = f.v;
    }
    // compact ext frag (scaled): A[row r][k0..4] = {wih_hi, wih_hi, wih_lo, gb_hi, gb_lo}
    {
        int tt = tid >> 4, r = tid & 15;
        int gi = tt >> 2;
        float scl = (gi == 2) ? TWO_L : -LOG2E;
        int G = gi * 64 + (tt & 3) * 16 + r;
        float wih = scl * Wih[G];
        float gb  = scl * (Bih[G] + Bhh[G]);
        unsigned short wh = f2bf(wih);
        unsigned short wl = f2bf(wih - bfh(wh));
        unsigned short gh = f2bf(gb);
        unsigned short gl = f2bf(gb - bfh(gh));
        union { bf16x8 v; unsigned u[4]; } f;
        f.u[0] = (unsigned)wh | ((unsigned)wh << 16);
        f.u[1] = (unsigned)wl | ((unsigned)gh << 16);
        f.u[2] = (unsigned)gl;
        f.u[3] = 0u;
        *(bf16x8*)(smem + OFF_EXT + tt * 256 + r * 16) = f.v;
    }
    if (tid < 4) ((float*)(smem + OFF_ZERO))[tid] = 0.0f;
    // mog tables: pi-permuted AND pre-scaled by -log2e (sig args in exp2 units)
    if (tid < 64) {
        int s = permk(tid);
        mogf[M0W + tid] = -LOG2E * M0w[s];
        mogf[M2W + tid] = -LOG2E * M2w[s];
        mogf[M4W + tid] = -LOG2E * M4w[s];
        mogf[M1W + tid] = -LOG2E * M1w[s];
        mogf[M1B + tid] = -LOG2E * M1b[s];
        mogf[M3W + tid] = -LOG2E * M3w[s];
        mogf[M3B + tid] = -LOG2E * M3b[s];
    }
    for (int i = tid; i < 320; i += NTHREADS)
        mogf[WPo + i] = Wp[(i & ~63) + permk(i & 63)];
    if (tid < 5) mogf[BPo + tid] = Bp[tid];
    __syncthreads();

    // ===================== mogrifier-LSTM recurrence =====================
    const int lane = tid & 63;
    const int wv   = tid >> 6;       // wave 0..3 -> rows wv*16..+15
    const int g_   = lane >> 4;      // 0..3
    const int n    = lane & 15;      // batchrow within wave (A-row / D-col)
    const int myrow = wv * 16 + n;

    const char* extb    = smem + ((g_ == 0) ? (OFF_EXT + n * 16) : OFF_ZERO);
    const int   extstep = (g_ == 0) ? 256 : 0;
    const float m0b_s = -LOG2E * M0b[0];
    const float m2b_s = -LOG2E * M2b[0];
    const float m4b_s = -LOG2E * M4b[0];

    // hB[4u+e] = h[unit 16u + 4g_ + e] of row n (fp32; equals B-frag order via pi)
    float hB[16];
    f32x4 cst[4];
    #pragma unroll
    for (int i = 0; i < 16; ++i) hB[i] = 0.0f;
    #pragma unroll
    for (int u = 0; u < 4; ++u) cst[u] = (f32x4){0.0f, 0.0f, 0.0f, 0.0f};

// q is already -L*(dot+bias); 2*sig = rcp(0.5 + 0.5*exp2(q))
#define MOG_DOT(MOFF, BIAS)                                                   \
    {                                                                         \
        float4 w0 = *(const float4*)&mogf[(MOFF) + g_ * 8];                   \
        float4 w1 = *(const float4*)&mogf[(MOFF) + g_ * 8 + 4];               \
        float4 w2 = *(const float4*)&mogf[(MOFF) + 32 + g_ * 8];              \
        float4 w3 = *(const float4*)&mogf[(MOFF) + 32 + g_ * 8 + 4];          \
        float p = w0.x*hB[0] + w0.y*hB[1] + w0.z*hB[2] + w0.w*hB[3]           \
                + w1.x*hB[4] + w1.y*hB[5] + w1.z*hB[6] + w1.w*hB[7]           \
                + w2.x*hB[8] + w2.y*hB[9] + w2.z*hB[10] + w2.w*hB[11]         \
                + w3.x*hB[12] + w3.y*hB[13] + w3.z*hB[14] + w3.w*hB[15];      \
        p += __shfl_xor(p, 16);                                               \
        p += __shfl_xor(p, 32);                                               \
        float t_ = fast_exp2(p + (BIAS));                                     \
        xt *= fast_rcp(0.5f + 0.5f * t_);                                     \
    }

#define MOG_SCALE(WOFF, BOFF)                                                 \
    {                                                                         \
        _Pragma("unroll")                                                     \
        for (int kc = 0; kc < 2; ++kc) {                                      \
            _Pragma("unroll")                                                 \
            for (int q = 0; q < 2; ++q) {                                     \
                float4 w4 = *(const float4*)&mogf[(WOFF) + kc*32 + g_*8 + q*4]; \
                float4 b4 = *(const float4*)&mogf[(BOFF) + kc*32 + g_*8 + q*4]; \
                int bse = kc * 8 + q * 4;                                     \
                hB[bse+0] *= fast_rcp(0.5f + 0.5f * fast_exp2(xt * w4.x + b4.x)); \
                hB[bse+1] *= fast_rcp(0.5f + 0.5f * fast_exp2(xt * w4.y + b4.y)); \
                hB[bse+2] *= fast_rcp(0.5f + 0.5f * fast_exp2(xt * w4.z + b4.z)); \
                hB[bse+3] *= fast_rcp(0.5f + 0.5f * fast_exp2(xt * w4.w + b4.w)); \
            }                                                                 \
        }                                                                     \
    }

    #pragma unroll 1
    for (int t = 0; t < TSTEPS; ++t) {
        float xt = (float)sXseqH[t * 64 + myrow];   // fp16 broadcast ds_read

        // ---- mogrifier (prescaled args, folded 2x) ----
        MOG_DOT(M0W, m0b_s)
        MOG_SCALE(M1W, M1B)
        MOG_DOT(M2W, m2b_s)
        MOG_SCALE(M3W, M3B)
        MOG_DOT(M4W, m4b_s)

        // ---- B-frags: h -> split bf16 ----
        union uf8 { bf16x8 v; unsigned u[4]; };
        uf8 bhi0, bhi1, blo0, blo1, bext;
        #pragma unroll
        for (int kc = 0; kc < 2; ++kc) {
            #pragma unroll
            for (int jp = 0; jp < 4; ++jp) {
                float a = hB[kc * 8 + 2 * jp], b = hB[kc * 8 + 2 * jp + 1];
                unsigned hi = cvt_pk_bf16(a, b);
                float ah = __uint_as_float(hi << 16);
                float bh = __uint_as_float(hi & 0xffff0000u);
                unsigned lo = cvt_pk_bf16(a - ah, b - bh);
                if (kc == 0) { bhi0.u[jp] = hi; blo0.u[jp] = lo; }
                else         { bhi1.u[jp] = hi; blo1.u[jp] = lo; }
            }
        }
        {   // ext B: k-slots {xt_hi, xt_lo, xt_hi, 1, 1, 0, 0, 0}
            unsigned xh = cvt_pk_bf16(xt, xt) & 0xffffu;
            float xl = xt - bfh((unsigned short)xh);
            unsigned xlp = cvt_pk_bf16(xl, xl) & 0xffffu;
            bext.u[0] = xh | (xlp << 16);
            bext.u[1] = xh | (0x3F80u << 16);
            bext.u[2] = 0x3F80u;
            bext.u[3] = 0u;
        }

        // gates (exp2-units) = scl*(Whh@h + xt*Wih + b)  (5 MFMAs per tile)
        auto gate_tile = [&](int tt) -> f32x4 {
            bf16x8 whi0 = WA[(tt * 2 + 0) * 64 + lane];
            bf16x8 whi1 = WA[(tt * 2 + 1) * 64 + lane];
            bf16x8 wext = *(const bf16x8*)(extb + tt * extstep);
            f32x4 d = {0.0f, 0.0f, 0.0f, 0.0f};
            d = __builtin_amdgcn_mfma_f32_16x16x32_bf16(wext, bext.v, d, 0, 0, 0);
            d = __builtin_amdgcn_mfma_f32_16x16x32_bf16(whi0, bhi0.v, d, 0, 0, 0);
            d = __builtin_amdgcn_mfma_f32_16x16x32_bf16(whi1, bhi1.v, d, 0, 0, 0);
            d = __builtin_amdgcn_mfma_f32_16x16x32_bf16(whi0, blo0.v, d, 0, 0, 0);
            d = __builtin_amdgcn_mfma_f32_16x16x32_bf16(whi1, blo1.v, d, 0, 0, 0);
            return d;
        };

        // ---- per unit-group u: fused activations (8 trans/element) ----
        // ai = -L*i, af = -L*f, ag = 2L*g, ao = -L*o  (directly exp2-ready)
        #pragma unroll
        for (int u = 0; u < 4; ++u) {
            f32x4 ai = gate_tile(u);
            f32x4 af = gate_tile(4 + u);
            f32x4 ag = gate_tile(8 + u);
            f32x4 ao = gate_tile(12 + u);
            #pragma unroll
            for (int e = 0; e < 4; ++e) {
                // sig(i)*tanh(g) = (B-1)/((1+A)(1+B)); A=inf -> r=0 -> 0 (correct)
                float A  = fast_exp2(ai[e]);
                float Bg = fminf(fast_exp2(ag[e]), 3.0e8f);
                float r  = fast_rcp((1.0f + A) * (1.0f + Bg));
                float p1 = (Bg - 1.0f) * r;
                float sf = fast_rcp(1.0f + fast_exp2(af[e]));      // sig(f)
                float cc = sf * cst[u][e] + p1;
                cst[u][e] = cc;
                float Ao = fast_exp2(ao[e]);
                float Bc = fminf(fast_exp2(TWO_L * cc), 3.0e8f);
                float rc = fast_rcp((1.0f + Ao) * (1.0f + Bc));
                hB[u * 4 + e] = (Bc - 1.0f) * rc;                  // sig(o)*tanh(c)
            }
        }
    }

    // ===================== projection: out = h @ Wp^T + Bp =====================
    #pragma unroll
    for (int p = 0; p < 5; ++p) {
        float ap = 0.0f;
        #pragma unroll
        for (int kc = 0; kc < 2; ++kc) {
            #pragma unroll
            for (int q = 0; q < 2; ++q) {
                float4 w = *(const float4*)&mogf[WPo + p * 64 + kc * 32 + g_ * 8 + q * 4];
                ap += w.x * hB[kc * 8 + q * 4 + 0] + w.y * hB[kc * 8 + q * 4 + 1]
                    + w.z * hB[kc * 8 + q * 4 + 2] + w.w * hB[kc * 8 + q * 4 + 3];
            }
        }
        ap += __shfl_xor(ap, 16);
        ap += __shfl_xor(ap, 32);
        if (g_ == 0)
            out[(rowbase + myrow) * 5 + p] = ap + mogf[BPo + p];
    }
}

extern "C" void kernel_launch(void* const* d_in, const int* in_sizes, int n_in,
                              void* d_out, int out_size, void* d_ws, size_t ws_size,
                              hipStream_t stream) {
    const float* x   = (const float*)d_in[0];
    const float* W1  = (const float*)d_in[1];
    const float* B1  = (const float*)d_in[2];
    const float* W2  = (const float*)d_in[3];
    const float* B2  = (const float*)d_in[4];
    const float* W3  = (const float*)d_in[5];
    const float* B3  = (const float*)d_in[6];
    const float* W4  = (const float*)d_in[7];
    const float* B4  = (const float*)d_in[8];
    const float* M0w = (const float*)d_in[9];
    const float* M0b = (const float*)d_in[10];
    const float* M1w = (const float*)d_in[11];
    const float* M1b = (const float*)d_in[12];
    const float* M2w = (const float*)d_in[13];
    const float* M2b = (const float*)d_in[14];
    const float* M3w = (const float*)d_in[15];
    const float* M3b = (const float*)d_in[16];
    const float* M4w = (const float*)d_in[17];
    const float* M4b = (const float*)d_in[18];
    const float* Wih = (const float*)d_in[19];
    const float* Bih = (const float*)d_in[20];
    const float* Whh = (const float*)d_in[21];
    const float* Bhh = (const float*)d_in[22];
    const float* Wp  = (const float*)d_in[23];
    const float* Bp  = (const float*)d_in[24];

    int B = in_sizes[0] / HID;          // 262144
    int nblocks = B / ROWS_PB;          // 4096

    hipLaunchKernelGGL(moglstm_mfma9, dim3(nblocks), dim3(NTHREADS), 0, stream,
                       x, W1, B1, W2, B2, W3, B3, W4, B4,
                       M0w, M0b, M1w, M1b, M2w, M2b, M3w, M3b, M4w, M4b,
                       Wih, Bih, Whh, Bhh, Wp, Bp, (float*)d_out);
}